// Round 1
// baseline (979.181 us; speedup 1.0000x reference)
//
#include <hip/hip_runtime.h>

#define NROWS 1048576
#define D 128
#define S 4096

typedef __bf16 bf16;
typedef __attribute__((ext_vector_type(8))) __bf16 bf16x8;
typedef __attribute__((ext_vector_type(4))) __bf16 bf16x4;
typedef __attribute__((ext_vector_type(4))) float f32x4;

// ---------------------------------------------------------------------------
// Kernel Z: zero xs accumulator in workspace; pre-convert Gamma_W -> bf16
// ---------------------------------------------------------------------------
__global__ __launch_bounds__(256) void k_init(const float* __restrict__ GW,
                                              float* __restrict__ xs,
                                              bf16* __restrict__ gwb) {
    int i = blockIdx.x * 256 + threadIdx.x;
    if (i < S * D) xs[i] = 0.f;
    if (i < D * D) gwb[i] = (bf16)GW[i];
}

// ---------------------------------------------------------------------------
// Kernel A: segment sum. seg_ids are sorted, so each thread accumulates in a
// register and only touches global atomics at segment boundaries.
// Block = 256 threads: thread t handles column (t&127) of row stream (t>>7),
// rows interleaved by 2 within a 256-row chunk. Loads are coalesced 256B/half-wave.
// ---------------------------------------------------------------------------
__global__ __launch_bounds__(256) void k_segsum(const float* __restrict__ x,
                                                const int* __restrict__ sid,
                                                float* __restrict__ xs) {
    __shared__ int ssid[256];
    const int t = threadIdx.x;
    const size_t r0 = (size_t)blockIdx.x * 256;
    ssid[t] = sid[r0 + t];
    __syncthreads();
    const int col = t & 127;
    const int st  = t >> 7;
    float acc = 0.f;
    int cur = ssid[st];
    for (int i = 0; i < 128; i += 4) {
        float v[4];
        int   s[4];
#pragma unroll
        for (int u = 0; u < 4; ++u) {
            int rl = 2 * (i + u) + st;
            v[u] = x[(r0 + rl) * D + col];
            s[u] = ssid[rl];
        }
#pragma unroll
        for (int u = 0; u < 4; ++u) {
            if (s[u] != cur) {                 // wave-uniform branch (same row per half-wave)
                atomicAdd(&xs[(size_t)cur * D + col], acc);
                acc = 0.f;
                cur = s[u];
            }
            acc += v[u];
        }
    }
    atomicAdd(&xs[(size_t)cur * D + col], acc);
}

// ---------------------------------------------------------------------------
// Kernel B: v[s][j] = Gamma_b[j] - sum_k xs[s][k] * Lambda_W[j][k]
// Lambda staged in LDS with row stride 129 (bank-conflict-free: bank=(j+k)%32).
// 128 threads (thread j), 8 segments per block.
// ---------------------------------------------------------------------------
#define SEGS_PER_BLOCK 8
__global__ __launch_bounds__(128) void k_lambda(const float* __restrict__ xs,
                                                const float* __restrict__ LW,
                                                const float* __restrict__ gb,
                                                float* __restrict__ v) {
    __shared__ float L[128 * 129];
    __shared__ float xrow[128];
    const int t = threadIdx.x;
    for (int i = 0; i < 128; ++i)            // coalesced: row i, col t
        L[i * 129 + t] = LW[i * 128 + t];
    const float bj = gb[t];
    for (int sl = 0; sl < SEGS_PER_BLOCK; ++sl) {
        const int s = blockIdx.x * SEGS_PER_BLOCK + sl;
        __syncthreads();                      // also covers L on first iter
        xrow[t] = xs[(size_t)s * D + t];
        __syncthreads();
        float acc = 0.f;
#pragma unroll 8
        for (int k = 0; k < 128; ++k)
            acc += xrow[k] * L[t * 129 + k];  // xrow[k]: broadcast; L: conflict-free
        v[(size_t)s * D + t] = bj - acc;
    }
}

// ---------------------------------------------------------------------------
// Kernel C: out[r][j] = sum_k x[r][k]*Gamma[j][k] + v[seg[r]][j]
// bf16 MFMA 16x16x32. Block = 256 threads (4 waves), tile M=128 x N=128, K=128.
// A (x rows, fp32->bf16) and B (Gamma bf16) staged in LDS, row stride 136 bf16
// (272B) -> only 2-way bank aliasing on ds_read_b128 fragment loads (free).
// Each wave computes a 64x64 sub-tile = 4x4 MFMA tiles.
// ---------------------------------------------------------------------------
__global__ __launch_bounds__(256) void k_main(const float* __restrict__ x,
                                              const int* __restrict__ sid,
                                              const bf16* __restrict__ gwb,
                                              const float* __restrict__ v,
                                              float* __restrict__ out) {
    __shared__ bf16 As[128 * 136];
    __shared__ bf16 Bs[128 * 136];
    __shared__ int  ssid[128];
    const int t = threadIdx.x;
    const size_t r0 = (size_t)blockIdx.x * 128;

    if (t < 128) ssid[t] = sid[r0 + t];

    // Stage Gamma (bf16, row-major [j][k]) -> Bs. 2048 x 16B slots.
#pragma unroll
    for (int i = 0; i < 8; ++i) {
        int idx = i * 256 + t;       // slot of 8 bf16
        int row = idx >> 4;          // 16 slots per 128-col row
        int k8  = idx & 15;
        bf16x8 val = *(const bf16x8*)(gwb + (size_t)idx * 8);
        *(bf16x8*)&Bs[row * 136 + k8 * 8] = val;
    }

    // Stage x tile (fp32 -> bf16) -> As. 4096 x float4 slots, coalesced.
#pragma unroll
    for (int i = 0; i < 16; ++i) {
        int idx = i * 256 + t;       // slot of 4 floats
        int row = idx >> 5;          // 32 float4 per row
        int c4  = idx & 31;
        float4 xv = *(const float4*)(x + r0 * D + (size_t)idx * 4);
        bf16x4 bv;
        bv[0] = (bf16)xv.x; bv[1] = (bf16)xv.y; bv[2] = (bf16)xv.z; bv[3] = (bf16)xv.w;
        *(bf16x4*)&As[row * 136 + c4 * 4] = bv;
    }
    __syncthreads();

    const int wave = t >> 6, lane = t & 63;
    const int wm = (wave >> 1) * 64;   // M-half of this wave
    const int wn = (wave & 1) * 64;    // N-half of this wave
    const int lm = lane & 15, quad = lane >> 4;

    f32x4 acc[4][4];
#pragma unroll
    for (int mi = 0; mi < 4; ++mi)
#pragma unroll
        for (int ni = 0; ni < 4; ++ni)
            acc[mi][ni] = (f32x4){0.f, 0.f, 0.f, 0.f};

#pragma unroll
    for (int kb = 0; kb < 128; kb += 32) {
        bf16x8 af[4], bb[4];
#pragma unroll
        for (int mi = 0; mi < 4; ++mi)
            af[mi] = *(const bf16x8*)&As[(wm + mi * 16 + lm) * 136 + kb + quad * 8];
#pragma unroll
        for (int ni = 0; ni < 4; ++ni)
            bb[ni] = *(const bf16x8*)&Bs[(wn + ni * 16 + lm) * 136 + kb + quad * 8];
#pragma unroll
        for (int mi = 0; mi < 4; ++mi)
#pragma unroll
            for (int ni = 0; ni < 4; ++ni)
                acc[mi][ni] = __builtin_amdgcn_mfma_f32_16x16x32_bf16(
                    af[mi], bb[ni], acc[mi][ni], 0, 0, 0);
    }

    // Epilogue: C/D layout col = lane&15 (N), row = quad*4 + reg (M).
#pragma unroll
    for (int mi = 0; mi < 4; ++mi) {
        const int rbase = wm + mi * 16 + quad * 4;
#pragma unroll
        for (int reg = 0; reg < 4; ++reg) {
            const int rl = rbase + reg;
            const int s = ssid[rl];
            const float* vrow = v + (size_t)s * D;
            const size_t obase = (r0 + rl) * D;
#pragma unroll
            for (int ni = 0; ni < 4; ++ni) {
                const int j = wn + ni * 16 + lm;
                out[obase + j] = acc[mi][ni][reg] + vrow[j];
            }
        }
    }
}

// ---------------------------------------------------------------------------
extern "C" void kernel_launch(void* const* d_in, const int* in_sizes, int n_in,
                              void* d_out, int out_size, void* d_ws, size_t ws_size,
                              hipStream_t stream) {
    const float* x   = (const float*)d_in[0];
    const int*   sid = (const int*)d_in[1];
    // d_in[2] = num_segments scalar (value 4096), compile-time constant here
    const float* GW  = (const float*)d_in[3];
    const float* gb  = (const float*)d_in[4];
    const float* LW  = (const float*)d_in[5];
    float* out = (float*)d_out;

    float* xs  = (float*)d_ws;            // [S*D] fp32, 2 MB
    float* v   = xs + S * D;              // [S*D] fp32, 2 MB  (v = Gamma_b - xm)
    bf16*  gwb = (bf16*)(v + S * D);      // [D*D] bf16, 32 KB

    k_init  <<<(S * D + 255) / 256, 256, 0, stream>>>(GW, xs, gwb);
    k_segsum<<<NROWS / 256,          256, 0, stream>>>(x, sid, xs);
    k_lambda<<<S / SEGS_PER_BLOCK,   128, 0, stream>>>(xs, LW, gb, v);
    k_main  <<<NROWS / 128,          256, 0, stream>>>(x, sid, gwb, v, out);
}